// Round 17
// baseline (55.808 us; speedup 1.0000x reference)
//
#include <hip/hip_runtime.h>
#include <hip/hip_bf16.h>

typedef __attribute__((ext_vector_type(8))) short bf16x8;
typedef __attribute__((ext_vector_type(16))) float f32x16;

#define DHEAD 64
#define L_SEQ 2048
// softmax scale 1/8 folded with log2(e): exp(x/8) == exp2(x*QSCALE)
#define QSCALE (0.125f * 1.44269504088896340736f)

// ws layout (round-14/16, proven): [4KB, 4KB+2MB) ml float2[(bh*16+T)*4+seg][128];
// [4KB+2MB, +12.6MB) seg>=1 bf16 partial O, compact slots [768][128][64]
#define WS_ML_OFF   4096
#define WS_PART_OFF (4096 + 2048 * 128 * 8)
#define WS_NEED     ((size_t)WS_PART_OFF + (size_t)768 * 128 * 64 * 2)

union U4S8 { uint4 u; bf16x8 s; };

// Single-instruction f32x2 -> bf16x2 pack (RNE); no builtin on gfx950.
__device__ __forceinline__ unsigned pk2(float a, float b) {
    unsigned r;
    asm("v_cvt_pk_bf16_f32 %0, %1, %2" : "=v"(r) : "v"(a), "v"(b));
    return r;
}
__device__ __forceinline__ float bfrt(float x) {
    return __uint_as_float(pk2(x, x) << 16);
}
__device__ __forceinline__ float bf2f(unsigned short u) {
    return __uint_as_float((unsigned)u << 16);
}

__device__ __forceinline__ float fexp2(float x) {
#if __has_builtin(__builtin_amdgcn_exp2f)
    return __builtin_amdgcn_exp2f(x);
#else
    return __expf(x * 0.69314718055994530942f);
#endif
}

// Depth-4 trees, constant-index only (rule #20: runtime-indexing p -> scratch).
#define MAX16(P) fmaxf(fmaxf(fmaxf(fmaxf(P[0],P[1]),fmaxf(P[2],P[3])),          \
                             fmaxf(fmaxf(P[4],P[5]),fmaxf(P[6],P[7]))),         \
                       fmaxf(fmaxf(fmaxf(P[8],P[9]),fmaxf(P[10],P[11])),        \
                             fmaxf(fmaxf(P[12],P[13]),fmaxf(P[14],P[15]))))
#define SUM16(P) ((((P[0]+P[1])+(P[2]+P[3]))+((P[4]+P[5])+(P[6]+P[7])))         \
                + (((P[8]+P[9])+(P[10]+P[11]))+((P[12]+P[13])+(P[14]+P[15]))))

// Round-17: r16's staging (load->convert->write between barriers) exposed the
// full L2/HBM latency to all 4 waves every tile. Fix: 64-key tiles keep
// staging state at 32 regs, so r8's issue-early/write-late fits the register
// budget (r15's spill was 64 held regs). LDS double-buffer 2x16KB = 32KB,
// ONE barrier per tile:
//   [issue loads t+1][compute buf cur][convert+write buf cur^1] barrier
// write(nxt) vs read(cur) never alias; cross-iteration hazards covered by
// the end-of-iter barrier.
//
// LDS chunk map (16B slots; every ds op chunk_base + lane*16, conflict-free):
//  K chunk kb*4+kc, slot l: K[kb*32+(l&31)][kc*16+8*(l>>5)+j]   (kb=0,1)
//  V chunk kv*2+dt, slot l: V[kv*16+8*(l>>5)+j][dt*32+(l&31)]   (kv=0..3)

// Job table (per bh): 40 contiguous chunks of <=4 128-key units, LPT order.
// Entry = (T<<2)|seg; chunk covers 128-key units [4*seg, min(4*seg+3, T)].
__constant__ unsigned char JOBS[40] = {
    (15<<2)|0, (15<<2)|1, (15<<2)|2, (15<<2)|3,
    (14<<2)|0, (14<<2)|1, (14<<2)|2,
    (13<<2)|0, (13<<2)|1, (13<<2)|2,
    (12<<2)|0, (12<<2)|1, (12<<2)|2,
    (11<<2)|0, (11<<2)|1, (11<<2)|2,
    (10<<2)|0, (10<<2)|1,
    ( 9<<2)|0, ( 9<<2)|1,
    ( 8<<2)|0, ( 8<<2)|1,
    ( 7<<2)|0, ( 7<<2)|1,
    ( 6<<2)|0, ( 5<<2)|0, ( 4<<2)|0, ( 3<<2)|0,
    (14<<2)|3, (10<<2)|2, ( 6<<2)|1, ( 2<<2)|0,
    (13<<2)|3, ( 9<<2)|2, ( 5<<2)|1, ( 1<<2)|0,
    (12<<2)|3, ( 8<<2)|2, ( 4<<2)|1, ( 0<<2)|0,
};

template<int MODE>   // 2 = chunked + merge; 0 = basic fallback (no ws)
__global__ __launch_bounds__(256, 3)
void fattn_kernel(const float* __restrict__ Qg, const float* __restrict__ Kg,
                  const float* __restrict__ Vg, float* __restrict__ Og,
                  char* __restrict__ wsBase) {
    __shared__ uint4 sK4[2][8][64];   // 16 KB
    __shared__ uint4 sV4[2][8][64];   // 16 KB

    const int tid  = threadIdx.x;
    const int lane = tid & 63;
    const int w    = tid >> 6;     // wave -> rows 32w..32w+31 of this block's q-tile
    const int hi   = lane >> 5;
    const int c    = lane & 31;

    const int id  = blockIdx.x;
    const int bh  = (id & 7) + 8 * ((id >> 3) & 3);   // 4 bh per XCD

    int T, sg, t0, te;             // t indices in 64-key tiles: [t0, te]
    if (MODE == 2) {
        const unsigned jb = JOBS[id >> 5];
        T  = jb >> 2;
        sg = jb & 3;
        t0 = 8 * sg;
        te = 2 * T + 1; if (te > t0 + 7) te = t0 + 7;
    } else {
        const int u_ = id >> 5;
        T = (u_ < 8) ? (15 - u_) : (u_ - 8);
        sg = 0; t0 = 0; te = 2 * T + 1;
    }

    const size_t base = (size_t)bh * L_SEQ * DHEAD;
    const int q0w = T * 128 + w * 32;     // this wave's q rows

    // ---- Q fragments (B-operand), scale folded ----
    bf16x8 qf[4];
    {
        const float* Qrow = Qg + base + (size_t)(q0w + c) * DHEAD;
        #pragma unroll
        for (int kc = 0; kc < 4; ++kc) {
            float4 aa = *(const float4*)(Qrow + kc * 16 + hi * 8);
            float4 bb = *(const float4*)(Qrow + kc * 16 + hi * 8 + 4);
            U4S8 t;
            t.u = make_uint4(pk2(aa.x * QSCALE, aa.y * QSCALE),
                             pk2(aa.z * QSCALE, aa.w * QSCALE),
                             pk2(bb.x * QSCALE, bb.y * QSCALE),
                             pk2(bb.z * QSCALE, bb.w * QSCALE));
            qf[kc] = t.s;
        }
    }

    // ---- staging bases (64-key tile): thread (w,hi,c) ----
    // K: kb = w&1 (row 32*(w&1)+c), chunks (w&1)*4+(w>>1)*2 + {0,1},
    //    cols (w>>1)*32 + 8*hi + {0..7, 16..23}
    // V: kv = w (rows 16w+8hi+j), cols {c, 32+c}
    const float* Kpb = Kg + base + (size_t)(32 * (w & 1) + c) * DHEAD
                          + (w >> 1) * 32 + hi * 8;
    const float* Vpb = Vg + base + (size_t)(16 * w + 8 * hi) * DHEAD + c;
    const int kch = (w & 1) * 4 + (w >> 1) * 2;   // first K chunk this thread fills
    const int ksl = hi * 32 + c;                  // slot

    float4 rk[4];      // 16 f32
    float  rv[16];     // 16 f32  -> 32 staging regs held across compute

    auto load_tile = [&](int t64) {           // issue-early: in flight over compute
        const float* Kp = Kpb + (size_t)t64 * 64 * DHEAD;
        rk[0] = *(const float4*)(Kp + 0);
        rk[1] = *(const float4*)(Kp + 4);
        rk[2] = *(const float4*)(Kp + 16);
        rk[3] = *(const float4*)(Kp + 20);
        const float* Vp = Vpb + (size_t)t64 * 64 * DHEAD;
        #pragma unroll
        for (int j = 0; j < 8; ++j) {
            rv[j]     = Vp[j * DHEAD];
            rv[8 + j] = Vp[j * DHEAD + 32];
        }
    };

    auto write_tile = [&](int nb) {           // convert+write late
        sK4[nb][kch][ksl]     = make_uint4(pk2(rk[0].x, rk[0].y), pk2(rk[0].z, rk[0].w),
                                           pk2(rk[1].x, rk[1].y), pk2(rk[1].z, rk[1].w));
        sK4[nb][kch + 1][ksl] = make_uint4(pk2(rk[2].x, rk[2].y), pk2(rk[2].z, rk[2].w),
                                           pk2(rk[3].x, rk[3].y), pk2(rk[3].z, rk[3].w));
        sV4[nb][w * 2][ksl]     = make_uint4(pk2(rv[0], rv[1]),  pk2(rv[2], rv[3]),
                                             pk2(rv[4], rv[5]),  pk2(rv[6], rv[7]));
        sV4[nb][w * 2 + 1][ksl] = make_uint4(pk2(rv[8], rv[9]),  pk2(rv[10], rv[11]),
                                             pk2(rv[12], rv[13]), pk2(rv[14], rv[15]));
    };

    f32x16 o0 = {0,0,0,0,0,0,0,0,0,0,0,0,0,0,0,0};
    f32x16 o1 = o0;
    float m_r = -1e30f, l_r = 0.f;

    load_tile(t0);
    write_tile(0);
    __syncthreads();

    for (int t64 = t0; t64 <= te; ++t64) {
        const int  cur = (t64 - t0) & 1;
        const bool pf  = (t64 < te);
        if (pf) load_tile(t64 + 1);       // T14: issue before compute

        // live 32-key blocks for this wave on this tile (causal):
        // block 2*t64+i is live iff 2*t64+i <= 4*T+w
        const int lim = 4 * T + w - 2 * t64 + 1;
        const int nkb = lim < 0 ? 0 : (lim > 2 ? 2 : lim);

        if (nkb > 0) {
            float p[2][16];

            // ---- S^T = K * Q^T ----
            __builtin_amdgcn_s_setprio(1);
            #pragma unroll
            for (int i = 0; i < 2; ++i) {
                if (i < nkb) {
                    f32x16 s = {0,0,0,0,0,0,0,0,0,0,0,0,0,0,0,0};
                    #pragma unroll
                    for (int kc = 0; kc < 4; ++kc) {
                        U4S8 t; t.u = sK4[cur][i * 4 + kc][lane];
                        s = __builtin_amdgcn_mfma_f32_32x32x16_bf16(t.s, qf[kc], s, 0, 0, 0);
                    }
                    #pragma unroll
                    for (int r = 0; r < 16; ++r) p[i][r] = s[r];
                }
            }
            __builtin_amdgcn_s_setprio(0);

            // diagonal 32x32 mask: compile-time index, runtime CONDITION only
            #pragma unroll
            for (int i = 0; i < 2; ++i) {
                if (2 * t64 + i == 4 * T + w) {
                    #pragma unroll
                    for (int r = 0; r < 16; ++r) {
                        const int kk = (r & 3) + 8 * (r >> 2) + 4 * hi;
                        if (kk > c) p[i][r] = -1e30f;
                    }
                }
            }

            // ---- online softmax over nkb*32 keys ----
            float mx = MAX16(p[0]);
            if (nkb > 1) mx = fmaxf(mx, MAX16(p[1]));
            mx = fmaxf(mx, __shfl_xor(mx, 32));

            if (__any(mx > m_r + 8.f)) {    // defer-max (T13)
                const float mn    = fmaxf(m_r, mx);
                const float alpha = fexp2(m_r - mn);
                m_r  = mn;
                l_r *= alpha;
                #pragma unroll
                for (int r = 0; r < 16; ++r) {
                    const float ab = __shfl(alpha, (r & 3) + 8 * (r >> 2) + 4 * hi);
                    o0[r] *= ab; o1[r] *= ab;
                }
            }

            #pragma unroll
            for (int i = 0; i < 2; ++i) {
                if (i < nkb) {
                    #pragma unroll
                    for (int r = 0; r < 16; ++r) p[i][r] = fexp2(p[i][r] - m_r);
                }
            }
            float rs = SUM16(p[0]);
            if (nkb > 1) rs += SUM16(p[1]);
            rs += __shfl_xor(rs, 32);
            l_r += rs;

            // ---- P -> A-frags (permlane32_swap) + O += P V ----
            __builtin_amdgcn_s_setprio(1);
            #pragma unroll
            for (int kcl = 0; kcl < 4; ++kcl) {
                if (kcl < 2 * nkb) {
                    const int i = kcl >> 1, bs = (kcl & 1) * 8;
                    unsigned a0 = pk2(p[i][bs + 0], p[i][bs + 1]);
                    unsigned a1 = pk2(p[i][bs + 2], p[i][bs + 3]);
                    unsigned b0 = pk2(p[i][bs + 4], p[i][bs + 5]);
                    unsigned b1 = pk2(p[i][bs + 6], p[i][bs + 7]);
                    asm("v_permlane32_swap_b32 %0, %1" : "+v"(a0), "+v"(b0));
                    asm("v_permlane32_swap_b32 %0, %1" : "+v"(a1), "+v"(b1));
                    U4S8 t;
                    t.u = make_uint4(a0, a1, b0, b1);
                    U4S8 tv0; tv0.u = sV4[cur][kcl * 2][lane];
                    o0 = __builtin_amdgcn_mfma_f32_32x32x16_bf16(t.s, tv0.s, o0, 0, 0, 0);
                    U4S8 tv1; tv1.u = sV4[cur][kcl * 2 + 1][lane];
                    o1 = __builtin_amdgcn_mfma_f32_32x32x16_bf16(t.s, tv1.s, o1, 0, 0, 0);
                }
            }
            __builtin_amdgcn_s_setprio(0);
        }

        if (pf) {                         // write-late into the OTHER buffer,
            write_tile(cur ^ 1);          // then one barrier per tile
            __syncthreads();
        }
    }

    float* Op = Og + base;

    if (MODE == 0 || T <= 3) {
        // ---- single contributor: normalize, store final ----
        const float linv = 1.f / l_r;
        #pragma unroll
        for (int r = 0; r < 16; ++r) {
            const int   cr  = (r & 3) + 8 * (r >> 2) + 4 * hi;
            const float lb  = __shfl(linv, cr);
            const int   row = q0w + cr;
            Op[(size_t)row * DHEAD + c]      = o0[r] * lb;
            Op[(size_t)row * DHEAD + 32 + c] = o1[r] * lb;
        }
        return;
    }

    // ---- publish partial, write-only; merge_kernel combines ----
    const int f4 = (bh * 16 + T) * 4;
    float2* ml = (float2*)(wsBase + WS_ML_OFF);
    if (hi == 0) ml[(size_t)(f4 + sg) * 128 + w * 32 + c] = make_float2(m_r, l_r);
    if (sg == 0) {          // seg0 partial (bf16-rounded, unnormalized) in d_out
        #pragma unroll
        for (int r = 0; r < 16; ++r) {
            const int cr  = (r & 3) + 8 * (r >> 2) + 4 * hi;
            const int row = q0w + cr;
            Op[(size_t)row * DHEAD + c]      = bfrt(o0[r]);
            Op[(size_t)row * DHEAD + 32 + c] = bfrt(o1[r]);
        }
    } else {                // seg>=1 partial as bf16 in compact ws slot
        const int g  = T >> 2;
        const int ps = bh * 24 + 2 * g * (g - 1) + (T & 3) * g + (sg - 1);
        unsigned short* mp = (unsigned short*)(wsBase + WS_PART_OFF) + (size_t)ps * 128 * 64;
        #pragma unroll
        for (int r = 0; r < 16; ++r) {
            const int cr   = (r & 3) + 8 * (r >> 2) + 4 * hi;
            const int lrow = w * 32 + cr;
            mp[lrow * 64 + c]      = (unsigned short)pk2(o0[r], o0[r]);
            mp[lrow * 64 + 32 + c] = (unsigned short)pk2(o1[r], o1[r]);
        }
    }
}

// n-way streaming merge: one block per (bh,T), exact online-softmax combine.
__global__ __launch_bounds__(256)
void merge_kernel(float* __restrict__ Og, const char* __restrict__ wsBase) {
    const int blk = blockIdx.x;           // 512 = 32 bh x 16 T
    const int bh = blk >> 4, T = blk & 15;
    if (T <= 3) return;                   // single contributor wrote final
    const int n  = (T >> 2) + 1;          // contributors 2..4
    const int f4 = (bh * 16 + T) * 4;
    const int g  = T >> 2;
    const int psb = bh * 24 + 2 * g * (g - 1) + (T & 3) * g;

    const float2* ml = (const float2*)(wsBase + WS_ML_OFF);
    const unsigned short* part = (const unsigned short*)(wsBase + WS_PART_OFF);
    const unsigned short* p1 = part + (size_t)(psb + 0) * 128 * 64;
    const unsigned short* p2 = part + (size_t)(psb + 1) * 128 * 64;
    const unsigned short* p3 = part + (size_t)(psb + 2) * 128 * 64;
    float* Op = Og + ((size_t)bh * L_SEQ + (size_t)T * 128) * DHEAD;

    __shared__ float sA0[128], sA1[128], sA2[128], sA3[128], sLi[128];
    const int t = threadIdx.x;
    if (t < 128) {
        const float2 m0 = ml[(size_t)(f4 + 0) * 128 + t];
        const float2 m1 = ml[(size_t)(f4 + 1) * 128 + t];
        const float2 m2 = (n > 2) ? ml[(size_t)(f4 + 2) * 128 + t] : make_float2(-1e30f, 0.f);
        const float2 m3 = (n > 3) ? ml[(size_t)(f4 + 3) * 128 + t] : make_float2(-1e30f, 0.f);
        const float mM = fmaxf(fmaxf(m0.x, m1.x), fmaxf(m2.x, m3.x));
        const float a0 = fexp2(m0.x - mM), a1 = fexp2(m1.x - mM);
        const float a2 = fexp2(m2.x - mM), a3 = fexp2(m3.x - mM);
        sA0[t] = a0; sA1[t] = a1; sA2[t] = a2; sA3[t] = a3;
        sLi[t] = 1.f / (a0 * m0.y + a1 * m1.y + a2 * m2.y + a3 * m3.y);
    }
    __syncthreads();

    #pragma unroll
    for (int e = 0; e < 8; ++e) {
        const int idx4 = e * 256 + t;     // 2048 float4 groups (128 rows x 16)
        const int row  = idx4 >> 4;
        const int c4   = (idx4 & 15) * 4;
        const int off  = row * 64 + c4;
        const float a0 = sA0[row], li = sLi[row];
        float4 po = *(float4*)&Op[off];
        po.x *= a0; po.y *= a0; po.z *= a0; po.w *= a0;
        {
            const float a1 = sA1[row];
            const ushort4 u = *(const ushort4*)&p1[off];
            po.x += a1 * bf2f(u.x); po.y += a1 * bf2f(u.y);
            po.z += a1 * bf2f(u.z); po.w += a1 * bf2f(u.w);
        }
        if (n > 2) {
            const float a2 = sA2[row];
            const ushort4 u = *(const ushort4*)&p2[off];
            po.x += a2 * bf2f(u.x); po.y += a2 * bf2f(u.y);
            po.z += a2 * bf2f(u.z); po.w += a2 * bf2f(u.w);
        }
        if (n > 3) {
            const float a3 = sA3[row];
            const ushort4 u = *(const ushort4*)&p3[off];
            po.x += a3 * bf2f(u.x); po.y += a3 * bf2f(u.y);
            po.z += a3 * bf2f(u.z); po.w += a3 * bf2f(u.w);
        }
        po.x *= li; po.y *= li; po.z *= li; po.w *= li;
        *(float4*)&Op[off] = po;
    }
}

extern "C" void kernel_launch(void* const* d_in, const int* in_sizes, int n_in,
                              void* d_out, int out_size, void* d_ws, size_t ws_size,
                              hipStream_t stream) {
    const float* Q = (const float*)d_in[0];
    const float* K = (const float*)d_in[1];
    const float* V = (const float*)d_in[2];
    float* O = (float*)d_out;
    if (ws_size >= WS_NEED) {
        fattn_kernel<2><<<dim3(1280), dim3(256), 0, stream>>>(Q, K, V, O, (char*)d_ws);
        merge_kernel<<<dim3(512), dim3(256), 0, stream>>>(O, (const char*)d_ws);
    } else {                                     // ws too small: fallback schedule
        fattn_kernel<0><<<dim3(512), dim3(256), 0, stream>>>(Q, K, V, O, (char*)d_ws);
    }
}

// Round 20
// 51.809 us; speedup vs baseline: 1.0772x; 1.0772x over previous
//
#include <hip/hip_runtime.h>
#include <hip/hip_bf16.h>

typedef __attribute__((ext_vector_type(8))) short bf16x8;
typedef __attribute__((ext_vector_type(16))) float f32x16;

#define DHEAD 64
#define L_SEQ 2048
// softmax scale 1/8 folded with log2(e): exp(x/8) == exp2(x*QSCALE)
#define QSCALE (0.125f * 1.44269504088896340736f)

// ws layout: [4KB, 4KB+1MB) ml float2[512][2][128];
// [4KB+1MB, +8MB) h=1 bf16 partial O [512][128][64]
#define WS_ML_OFF   4096
#define WS_PART_OFF (4096 + 512 * 2 * 128 * 8)
#define WS_NEED     ((size_t)WS_PART_OFF + (size_t)512 * 128 * 64 * 2)

union U4S8 { uint4 u; bf16x8 s; };

// Single-instruction f32x2 -> bf16x2 pack (RNE); no builtin on gfx950.
__device__ __forceinline__ unsigned pk2(float a, float b) {
    unsigned r;
    asm("v_cvt_pk_bf16_f32 %0, %1, %2" : "=v"(r) : "v"(a), "v"(b));
    return r;
}
__device__ __forceinline__ float bfrt(float x) {
    return __uint_as_float(pk2(x, x) << 16);
}
__device__ __forceinline__ float bf2f(unsigned short u) {
    return __uint_as_float((unsigned)u << 16);
}

__device__ __forceinline__ float fexp2(float x) {
#if __has_builtin(__builtin_amdgcn_exp2f)
    return __builtin_amdgcn_exp2f(x);
#else
    return __expf(x * 0.69314718055994530942f);
#endif
}

// Cross-half (lane ^ 32) reductions.
// r18 failed: two "+v" operands with identical SSA value got coalesced into
// ONE register (swap(r,r) loses the lane's own value).
// r19 failed: v_mov + v_permlane32_swap back-to-back INSIDE one asm block —
// VALU-write -> lane-crossing-read hazard needs wait states the compiler
// can't insert inside the asm. (P-pack swaps work: inputs come from separate
// pk2 asm statements with scheduler distance.)
// Fix: the documented BUILTIN — compiler owns regalloc AND hazard nops.
// Returns uint32x2 {vdst', vsrc'}; with both inputs = x each lane gets
// {x[l], x[l^32]} in some order -> max/sum are orientation-independent.
#if __has_builtin(__builtin_amdgcn_permlane32_swap)
__device__ __forceinline__ float xhalf_max(float x) {
    const unsigned u = __float_as_uint(x);
    const auto r = __builtin_amdgcn_permlane32_swap(u, u, false, false);
    return fmaxf(__uint_as_float(r[0]), __uint_as_float(r[1]));
}
__device__ __forceinline__ float xhalf_sum(float x) {
    const unsigned u = __float_as_uint(x);
    const auto r = __builtin_amdgcn_permlane32_swap(u, u, false, false);
    return __uint_as_float(r[0]) + __uint_as_float(r[1]);
}
#else
__device__ __forceinline__ float xhalf_max(float x) { return fmaxf(x, __shfl_xor(x, 32)); }
__device__ __forceinline__ float xhalf_sum(float x) { return x + __shfl_xor(x, 32); }
#endif

// Depth-4 trees, constant-index only (rule #20: runtime-indexing p -> scratch).
#define MAX16(P) fmaxf(fmaxf(fmaxf(fmaxf(P[0],P[1]),fmaxf(P[2],P[3])),          \
                             fmaxf(fmaxf(P[4],P[5]),fmaxf(P[6],P[7]))),         \
                       fmaxf(fmaxf(fmaxf(P[8],P[9]),fmaxf(P[10],P[11])),        \
                             fmaxf(fmaxf(P[12],P[13]),fmaxf(P[14],P[15]))))
#define SUM16(P) ((((P[0]+P[1])+(P[2]+P[3]))+((P[4]+P[5])+(P[6]+P[7])))         \
                + (((P[8]+P[9])+(P[10]+P[11]))+((P[12]+P[13])+(P[14]+P[15]))))

// Body = round-13 (best measured, 52.1us: VGPR 84, no spill, 0 conflicts):
// p[2][16] diet, single-buffered 32KB LDS, stage_K/stage_V load->write
// immediately (NO reg prefetch: r15 proved the allocator spills it).
// Schedule: 1024 jobs = 32 bh x 16 T x 2 kv-parities, LPT; merge_kernel
// combines partials (r10 lesson: no in-launch cross-block sync).
// LDS chunk map (all ds ops chunk_base + lane*16, conflict-free):
//  K chunk kb*4+kc, slot l: K[kb*32+(l&31)][kc*16+8*(l>>5)+j]
//  V chunk kv*2+dt, slot l: V[kv*16+8*(l>>5)+j][dt*32+(l&31)]  (kv=0..7)

template<int SPLIT>
__global__ __launch_bounds__(256, 3)
void fattn_kernel(const float* __restrict__ Qg, const float* __restrict__ Kg,
                  const float* __restrict__ Vg, float* __restrict__ Og,
                  char* __restrict__ wsBase) {
    __shared__ uint4 sK4[16][64];
    __shared__ uint4 sV4[16][64];

    const int tid  = threadIdx.x;
    const int lane = tid & 63;
    const int w    = tid >> 6;     // wave -> rows 32w..32w+31 of this block's q-tile
    const int hi   = lane >> 5;
    const int c    = lane & 31;

    const int id  = blockIdx.x;
    const int bh  = (id & 7) + 8 * ((id >> 3) & 3);   // 4 bh per XCD

    int T, h, kt0, kstep, d;
    if (SPLIT) {
        const int k31 = 31 - (id >> 5);   // rank 0 = heaviest (LPT)
        T = k31 >> 1;
        h = 1 - (k31 & 1);
        d = (T + 2 - h) >> 1;             // # kv tiles of parity h for q-tile T
        if (d == 0) return;               // T=0, h=1: empty job
        kt0 = h; kstep = 2;
    } else {                              // fallback schedule (no ws needed)
        const int u_ = id >> 5;
        T = (u_ < 8) ? (15 - u_) : (u_ - 8);
        h = 0; d = T + 1; kt0 = 0; kstep = 1;
    }

    const size_t base = (size_t)bh * L_SEQ * DHEAD;
    const int q0w = T * 128 + w * 32;     // this wave's q rows

    // ---- Q fragments (B-operand), scale folded ----
    bf16x8 qf[4];
    {
        const float* Qrow = Qg + base + (size_t)(q0w + c) * DHEAD;
        #pragma unroll
        for (int kc = 0; kc < 4; ++kc) {
            float4 aa = *(const float4*)(Qrow + kc * 16 + hi * 8);
            float4 bb = *(const float4*)(Qrow + kc * 16 + hi * 8 + 4);
            U4S8 t;
            t.u = make_uint4(pk2(aa.x * QSCALE, aa.y * QSCALE),
                             pk2(aa.z * QSCALE, aa.w * QSCALE),
                             pk2(bb.x * QSCALE, bb.y * QSCALE),
                             pk2(bb.z * QSCALE, bb.w * QSCALE));
            qf[kc] = t.s;
        }
    }

    // ---- staging bases: thread (w,hi,c) ----
    const float* Kpb = Kg + base + (size_t)(32 * w + c) * DHEAD + 32 * hi;
    const float* Vpb = Vg + base + (size_t)(32 * w + 16 * hi) * DHEAD + c;

    auto stage_K = [&](int kt) {          // 32 floats live peak
        float4 rk[8];
        const float* Kp = Kpb + (size_t)kt * 128 * DHEAD;
        #pragma unroll
        for (int t = 0; t < 8; ++t) rk[t] = *(const float4*)(Kp + 4 * t);
        #pragma unroll
        for (int q = 0; q < 2; ++q)
            #pragma unroll
            for (int hh = 0; hh < 2; ++hh) {
                const float4 r0 = rk[4 * q + 2 * hh], r1 = rk[4 * q + 2 * hh + 1];
                sK4[w * 4 + 2 * hi + q][hh * 32 + c] =
                    make_uint4(pk2(r0.x, r0.y), pk2(r0.z, r0.w),
                               pk2(r1.x, r1.y), pk2(r1.z, r1.w));
            }
    };
    auto stage_V = [&](int kt) {          // 32 floats live peak
        float rv[32];
        const float* Vp = Vpb + (size_t)kt * 128 * DHEAD;
        #pragma unroll
        for (int j = 0; j < 16; ++j) {
            rv[j]      = Vp[j * DHEAD];
            rv[16 + j] = Vp[j * DHEAD + 32];
        }
        #pragma unroll
        for (int dt = 0; dt < 2; ++dt)
            #pragma unroll
            for (int hh = 0; hh < 2; ++hh) {
                const int b = 16 * dt + 8 * hh;
                sV4[(2 * w + hi) * 2 + dt][hh * 32 + c] =
                    make_uint4(pk2(rv[b + 0], rv[b + 1]), pk2(rv[b + 2], rv[b + 3]),
                               pk2(rv[b + 4], rv[b + 5]), pk2(rv[b + 6], rv[b + 7]));
            }
    };

    f32x16 o0 = {0,0,0,0,0,0,0,0,0,0,0,0,0,0,0,0};
    f32x16 o1 = o0;
    float m_r = -1e30f, l_r = 0.f;

    stage_K(kt0);
    stage_V(kt0);
    __syncthreads();

    for (int j = 0; j < d; ++j) {
        const int  kt   = kt0 + j * kstep;
        const bool pf   = (j + 1 < d);
        const bool diag = (kt == T);

        // two 64-key sub-passes over the staged 128-key tile (p[2][16] diet)
        #pragma unroll
        for (int sub = 0; sub < 2; ++sub) {
            const int lim = diag ? (w + 1 - 2 * sub) : 2;   // live 32-key blocks
            const int nkb = lim < 0 ? 0 : (lim > 2 ? 2 : lim);
            if (nkb > 0) {
                float p[2][16];

                // ---- S^T = K * Q^T (kb_global = 2*sub + i) ----
                __builtin_amdgcn_s_setprio(1);
                #pragma unroll
                for (int i = 0; i < 2; ++i) {
                    if (i < nkb) {
                        f32x16 s = {0,0,0,0,0,0,0,0,0,0,0,0,0,0,0,0};
                        #pragma unroll
                        for (int kc = 0; kc < 4; ++kc) {
                            U4S8 t; t.u = sK4[(2 * sub + i) * 4 + kc][lane];
                            s = __builtin_amdgcn_mfma_f32_32x32x16_bf16(t.s, qf[kc], s, 0, 0, 0);
                        }
                        #pragma unroll
                        for (int r = 0; r < 16; ++r) p[i][r] = s[r];
                    }
                }
                __builtin_amdgcn_s_setprio(0);

                // diagonal mask: compile-time index, runtime CONDITION only
                #pragma unroll
                for (int i = 0; i < 2; ++i) {
                    if (diag && (2 * sub + i) == w) {
                        #pragma unroll
                        for (int r = 0; r < 16; ++r) {
                            const int kk = (r & 3) + 8 * (r >> 2) + 4 * hi;
                            if (kk > c) p[i][r] = -1e30f;
                        }
                    }
                }

                // ---- online softmax over nkb*32 keys ----
                float mx = MAX16(p[0]);
                if (nkb > 1) mx = fmaxf(mx, MAX16(p[1]));
                mx = xhalf_max(mx);               // builtin permlane32_swap

                if (__any(mx > m_r + 8.f)) {      // defer-max (T13)
                    const float mn    = fmaxf(m_r, mx);
                    const float alpha = fexp2(m_r - mn);
                    m_r  = mn;
                    l_r *= alpha;
                    #pragma unroll
                    for (int r = 0; r < 16; ++r) {
                        const float ab = __shfl(alpha, (r & 3) + 8 * (r >> 2) + 4 * hi);
                        o0[r] *= ab; o1[r] *= ab;
                    }
                }

                #pragma unroll
                for (int i = 0; i < 2; ++i) {
                    if (i < nkb) {
                        #pragma unroll
                        for (int r = 0; r < 16; ++r) p[i][r] = fexp2(p[i][r] - m_r);
                    }
                }
                float rs = SUM16(p[0]);
                if (nkb > 1) rs += SUM16(p[1]);
                rs = xhalf_sum(rs);               // builtin permlane32_swap
                l_r += rs;

                // ---- P -> A-frags (permlane32_swap) + O += P V ----
                __builtin_amdgcn_s_setprio(1);
                #pragma unroll
                for (int kcl = 0; kcl < 4; ++kcl) {
                    if (kcl < 2 * nkb) {
                        const int i = kcl >> 1, bs = (kcl & 1) * 8;
                        unsigned a0 = pk2(p[i][bs + 0], p[i][bs + 1]);
                        unsigned a1 = pk2(p[i][bs + 2], p[i][bs + 3]);
                        unsigned b0 = pk2(p[i][bs + 4], p[i][bs + 5]);
                        unsigned b1 = pk2(p[i][bs + 6], p[i][bs + 7]);
                        asm("v_permlane32_swap_b32 %0, %1" : "+v"(a0), "+v"(b0));
                        asm("v_permlane32_swap_b32 %0, %1" : "+v"(a1), "+v"(b1));
                        U4S8 t;
                        t.u = make_uint4(a0, a1, b0, b1);
                        const int kv = 4 * sub + kcl;        // 16-key V slice
                        U4S8 tv0; tv0.u = sV4[kv * 2][lane];
                        o0 = __builtin_amdgcn_mfma_f32_32x32x16_bf16(t.s, tv0.s, o0, 0, 0, 0);
                        U4S8 tv1; tv1.u = sV4[kv * 2 + 1][lane];
                        o1 = __builtin_amdgcn_mfma_f32_32x32x16_bf16(t.s, tv1.s, o1, 0, 0, 0);
                    }
                }
                __builtin_amdgcn_s_setprio(0);
            }
        }

        if (pf) {                           // single buffer: drain reads, restage
            __syncthreads();
            stage_K(kt + kstep);
            stage_V(kt + kstep);
            __syncthreads();
        }
    }

    float* Op = Og + base;

    if (!SPLIT || T == 0) {
        // ---- single contributor: normalize, store final ----
        const float linv = 1.f / l_r;
        #pragma unroll
        for (int r = 0; r < 16; ++r) {
            const int   cr  = (r & 3) + 8 * (r >> 2) + 4 * hi;
            const float lb  = __shfl(linv, cr);
            const int   row = q0w + cr;
            Op[(size_t)row * DHEAD + c]      = o0[r] * lb;
            Op[(size_t)row * DHEAD + 32 + c] = o1[r] * lb;
        }
        return;
    }

    // ---- publish partial, write-only; merge_kernel combines ----
    const int f = bh * 16 + T;
    float2* ml = (float2*)(wsBase + WS_ML_OFF);
    if (hi == 0) ml[((size_t)f * 2 + h) * 128 + w * 32 + c] = make_float2(m_r, l_r);
    if (h == 0) {           // h=0 partial lives (bf16-rounded, unnormalized) in d_out
        #pragma unroll
        for (int r = 0; r < 16; ++r) {
            const int cr  = (r & 3) + 8 * (r >> 2) + 4 * hi;
            const int row = q0w + cr;
            Op[(size_t)row * DHEAD + c]      = bfrt(o0[r]);
            Op[(size_t)row * DHEAD + 32 + c] = bfrt(o1[r]);
        }
    } else {                // h=1 partial as bf16 in ws
        unsigned short* mp = (unsigned short*)(wsBase + WS_PART_OFF) + (size_t)f * 128 * 64;
        #pragma unroll
        for (int r = 0; r < 16; ++r) {
            const int cr   = (r & 3) + 8 * (r >> 2) + 4 * hi;
            const int lrow = w * 32 + cr;
            mp[lrow * 64 + c]      = (unsigned short)pk2(o0[r], o0[r]);
            mp[lrow * 64 + 32 + c] = (unsigned short)pk2(o1[r], o1[r]);
        }
    }
}

// Streaming merge: one block per (bh,T), exact online-softmax combine.
__global__ __launch_bounds__(256)
void merge_kernel(float* __restrict__ Og, const char* __restrict__ wsBase) {
    const int blk = blockIdx.x;           // 512 = 32 bh x 16 T
    const int bh = blk >> 4, T = blk & 15;
    if (T == 0) return;                   // written final by fattn_kernel
    const int f = bh * 16 + T;

    const float2* ml = (const float2*)(wsBase + WS_ML_OFF);
    const unsigned short* part =
        (const unsigned short*)(wsBase + WS_PART_OFF) + (size_t)f * 128 * 64;
    float* Op = Og + ((size_t)bh * L_SEQ + (size_t)T * 128) * DHEAD;

    __shared__ float sA0[128], sA1[128], sLi[128];
    const int t = threadIdx.x;
    if (t < 128) {
        const float2 m0 = ml[((size_t)f * 2 + 0) * 128 + t];
        const float2 m1 = ml[((size_t)f * 2 + 1) * 128 + t];
        const float mM = fmaxf(m0.x, m1.x);
        const float a0 = fexp2(m0.x - mM);
        const float a1 = fexp2(m1.x - mM);
        sA0[t] = a0; sA1[t] = a1;
        sLi[t] = 1.f / (a0 * m0.y + a1 * m1.y);
    }
    __syncthreads();

    #pragma unroll
    for (int e = 0; e < 8; ++e) {
        const int idx4 = e * 256 + t;     // 2048 float4 groups (128 rows x 16)
        const int row  = idx4 >> 4;
        const int c4   = (idx4 & 15) * 4;
        const float a0 = sA0[row], a1 = sA1[row], li = sLi[row];
        float4 po = *(float4*)&Op[row * 64 + c4];
        const ushort4 u = *(const ushort4*)&part[row * 64 + c4];
        po.x = (a0 * po.x + a1 * bf2f(u.x)) * li;
        po.y = (a0 * po.y + a1 * bf2f(u.y)) * li;
        po.z = (a0 * po.z + a1 * bf2f(u.z)) * li;
        po.w = (a0 * po.w + a1 * bf2f(u.w)) * li;
        *(float4*)&Op[row * 64 + c4] = po;
    }
}

extern "C" void kernel_launch(void* const* d_in, const int* in_sizes, int n_in,
                              void* d_out, int out_size, void* d_ws, size_t ws_size,
                              hipStream_t stream) {
    const float* Q = (const float*)d_in[0];
    const float* K = (const float*)d_in[1];
    const float* V = (const float*)d_in[2];
    float* O = (float*)d_out;
    if (ws_size >= WS_NEED) {
        fattn_kernel<1><<<dim3(1024), dim3(256), 0, stream>>>(Q, K, V, O, (char*)d_ws);
        merge_kernel<<<dim3(512), dim3(256), 0, stream>>>(O, (const char*)d_ws);
    } else {                                     // ws too small: fallback schedule
        fattn_kernel<0><<<dim3(512), dim3(256), 0, stream>>>(Q, K, V, O, (char*)d_ws);
    }
}